// Round 8
// baseline (87.860 us; speedup 1.0000x reference)
//
#include <hip/hip_runtime.h>
#include <math.h>

#define NB 8192
#define NC 128
#define NJS 8          // j-slices (grid.y); slice = 1024 cols
#define JPT 8          // j-tiles of 128 per slice

typedef float v4f __attribute__((ext_vector_type(4)));

// ---------------------------------------------------------------- prep:
// per row: fp8 e4m3 cast (packed 4/lane), sum-of-squares (fp32), CE term
// (fp32); zero sums/cnt. 8 rows per 256-thr block, 32 lanes per row.
__global__ __launch_bounds__(256) void k_prep(const float* __restrict__ x,
                                              const int* __restrict__ tgt,
                                              unsigned* __restrict__ xq,   // NB*32 uints (4 fp8 each)
                                              float* __restrict__ sq,
                                              float* __restrict__ ce,
                                              float* __restrict__ sums,
                                              unsigned* __restrict__ cnt) {
    int row = blockIdx.x * 8 + (threadIdx.x >> 5);
    int l = threadIdx.x & 31;
    float4 v = ((const float4*)(x + row * NC))[l];
    unsigned p = __builtin_amdgcn_cvt_pk_fp8_f32(v.x, v.y, 0, false);
    p = __builtin_amdgcn_cvt_pk_fp8_f32(v.z, v.w, p, true);
    xq[row * 32 + l] = p;

    float ss = fmaf(v.x, v.x, fmaf(v.y, v.y, fmaf(v.z, v.z, v.w * v.w)));
    float mx = fmaxf(fmaxf(v.x, v.y), fmaxf(v.z, v.w));
#pragma unroll
    for (int off = 16; off; off >>= 1) {        // offsets <32: stay within half-wave
        ss += __shfl_xor(ss, off);
        mx = fmaxf(mx, __shfl_xor(mx, off));
    }
    float es = expf(v.x - mx) + expf(v.y - mx) + expf(v.z - mx) + expf(v.w - mx);
#pragma unroll
    for (int off = 16; off; off >>= 1) es += __shfl_xor(es, off);
    if (l == 0) {
        sq[row] = ss;
        ce[row] = mx + logf(es) - x[row * NC + tgt[row]];
    }
    if (blockIdx.x == 0 && threadIdx.x < 4) {
        if (threadIdx.x < 2) sums[threadIdx.x] = 0.0f;
        if (threadIdx.x == 2) *cnt = 0u;
    }
}

// ---------------------------------------------------------------- triplet:
// FP8 E4M3 MFMA GEMM, 64x128 block tile (wave = 32x64), A in regs,
// B DOUBLE-buffered (2 x 16 KB) + metadata (8 KB) = 40 KB LDS => exactly
// 4 blocks/CU, grid 1024 = exactly resident. Loop shape: barrier (drains
// the prefetch issued one full iteration ago ~ free) -> issue prefetch
// jt+1 -> compute jt. Prefetch coverage = whole compute phase; one
// barrier per iteration. B chunk-XOR-swizzled on the GLOBAL source
// address (global_load_lds LDS dest is fixed wave-base + lane*16).
__global__ __launch_bounds__(256, 4) void k_trip(const unsigned char* __restrict__ xq,
                                                 const int* __restrict__ tgt,
                                                 const float* __restrict__ sq,
                                                 float* __restrict__ pmax,   // [16][NB]
                                                 float* __restrict__ pmin) { // [16][NB]
    __shared__ unsigned char Bs[2][128 * 128];  // 2 x 16 KB
    __shared__ float sqs[1024];                 // 4 KB  (block's j-slice sq)
    __shared__ int   tjs[1024];                 // 4 KB  (block's j-slice tgt)

    const int tid = threadIdx.x;
    const int lane = tid & 63;
    const int w = tid >> 6;           // wave 0..3
    const int rh = w >> 1;            // row half (32 rows)
    const int ch = w & 1;             // col half (64 cols)
    const int i0 = blockIdx.x * 64;
    const int jbase = blockIdx.y * 1024;
    const int m = lane & 15;
    const int quad = lane >> 4;

    // ---- stage j-slice metadata via async-LDS ----
    __builtin_amdgcn_global_load_lds(
        (const __attribute__((address_space(1))) unsigned*)((const unsigned*)(sq + jbase) + (w * 64 + lane) * 4),
        (__attribute__((address_space(3))) unsigned*)(sqs + w * 256),
        16, 0, 0);
    __builtin_amdgcn_global_load_lds(
        (const __attribute__((address_space(1))) unsigned*)((const unsigned*)(tgt + jbase) + (w * 64 + lane) * 4),
        (__attribute__((address_space(3))) unsigned*)(tjs + w * 256),
        16, 0, 0);

    // ---- stage B tile 0 into buffer 0 (async) ----
#pragma unroll
    for (int c = 0; c < 4; ++c) {
        int L = w * 256 + c * 64 + lane;          // 16-B chunk index 0..1023
        int col = L >> 3, cc = L & 7;
        const unsigned char* src = xq + (size_t)(jbase + col) * 128 + ((cc ^ (col & 7)) << 4);
        __builtin_amdgcn_global_load_lds(
            (const __attribute__((address_space(1))) unsigned*)src,
            (__attribute__((address_space(3))) unsigned*)(&Bs[0][0] + (w * 256 + c * 64) * 16),
            16, 0, 0);
    }

    // ---- A fragments straight into registers (8 B/frag, once per block) ----
    long a[2][4];
#pragma unroll
    for (int tm = 0; tm < 2; ++tm)
#pragma unroll
        for (int ks = 0; ks < 4; ++ks) {
            int row = i0 + rh * 32 + tm * 16 + m;
            a[tm][ks] = *(const long*)(xq + (size_t)row * 128 + ks * 32 + quad * 8);
        }

    // ---- anchor targets for this lane's output rows ----
    int ti[2][4];
#pragma unroll
    for (int tm = 0; tm < 2; ++tm)
#pragma unroll
        for (int r = 0; r < 4; ++r)
            ti[tm][r] = tgt[i0 + rh * 32 + tm * 16 + quad * 4 + r];

    float mp[2][4], mn[2][4];
#pragma unroll
    for (int tm = 0; tm < 2; ++tm)
#pragma unroll
        for (int r = 0; r < 4; ++r) { mp[tm][r] = -3.0e38f; mn[tm][r] = 3.0e38f; }

#pragma unroll 2
    for (int jt = 0; jt < JPT; ++jt) {
        // drains the prefetch issued one full iteration ago (~free) and
        // ensures all waves are done reading the buffer we're about to fill
        __syncthreads();

        // ---- early-issue prefetch of NEXT B tile into the other buffer ----
        if (jt + 1 < JPT) {
            int jn = jbase + (jt + 1) * 128;
            unsigned char* Bnxt = &Bs[(jt + 1) & 1][0];
#pragma unroll
            for (int c = 0; c < 4; ++c) {
                int L = w * 256 + c * 64 + lane;
                int col = L >> 3, cc = L & 7;
                const unsigned char* src = xq + (size_t)(jn + col) * 128 + ((cc ^ (col & 7)) << 4);
                __builtin_amdgcn_global_load_lds(
                    (const __attribute__((address_space(1))) unsigned*)src,
                    (__attribute__((address_space(3))) unsigned*)(Bnxt + (w * 256 + c * 64) * 16),
                    16, 0, 0);
            }
        }

        const unsigned char* Bcur = &Bs[jt & 1][0];

        // ---- column metadata from LDS ----
        float sqj[4]; int tj[4];
#pragma unroll
        for (int tn = 0; tn < 4; ++tn) {
            int cloc = jt * 128 + ch * 64 + tn * 16 + m;
            sqj[tn] = sqs[cloc];
            tj[tn] = tjs[cloc];
        }

        // ---- MFMA over K=128 (4 x K=32 fp8) ----
        v4f acc[2][4];
        v4f z = {0.0f, 0.0f, 0.0f, 0.0f};
#pragma unroll
        for (int tm = 0; tm < 2; ++tm)
#pragma unroll
            for (int tn = 0; tn < 4; ++tn) acc[tm][tn] = z;

#pragma unroll
        for (int ks = 0; ks < 4; ++ks) {
            long b[4];
            int c8 = ks * 4 + quad;               // 8-B k-chunk index 0..15
#pragma unroll
            for (int tn = 0; tn < 4; ++tn) {
                int col = ch * 64 + tn * 16 + m;
                int off = col * 128 + ((((c8 >> 1) ^ (col & 7))) << 4) + ((c8 & 1) << 3);
                b[tn] = *(const long*)(Bcur + off);
            }
#pragma unroll
            for (int tm = 0; tm < 2; ++tm)
#pragma unroll
                for (int tn = 0; tn < 4; ++tn)
                    acc[tm][tn] = __builtin_amdgcn_mfma_f32_16x16x32_fp8_fp8(
                        a[tm][ks], b[tn], acc[tm][tn], 0, 0, 0);
        }

        // ---- fused epilogue: v = sqj - 2*dot (sqi added in k_tail) ----
#pragma unroll
        for (int tn = 0; tn < 4; ++tn) {
#pragma unroll
            for (int tm = 0; tm < 2; ++tm)
#pragma unroll
                for (int r = 0; r < 4; ++r) {
                    float v = fmaf(-2.0f, acc[tm][tn][r], sqj[tn]);
                    bool pos = (tj[tn] == ti[tm][r]);
                    mp[tm][r] = fmaxf(mp[tm][r], pos ? v : -3.0e38f);
                    mn[tm][r] = fminf(mn[tm][r], pos ? 3.0e38f : v);
                }
        }
    }

    // ---- reduce across the 16 lanes (lane&15) sharing each output row ----
#pragma unroll
    for (int off = 1; off < 16; off <<= 1) {
#pragma unroll
        for (int tm = 0; tm < 2; ++tm)
#pragma unroll
            for (int r = 0; r < 4; ++r) {
                mp[tm][r] = fmaxf(mp[tm][r], __shfl_xor(mp[tm][r], off));
                mn[tm][r] = fminf(mn[tm][r], __shfl_xor(mn[tm][r], off));
            }
    }
    // ---- plain stores to this wave's private (slice, row-range) ----
    if (m == 0) {
        int slice = blockIdx.y * 2 + ch;
        float* pm = pmax + (size_t)slice * NB + i0 + rh * 32;
        float* pn = pmin + (size_t)slice * NB + i0 + rh * 32;
#pragma unroll
        for (int tm = 0; tm < 2; ++tm)
#pragma unroll
            for (int r = 0; r < 4; ++r) {
                int rr = tm * 16 + quad * 4 + r;
                pm[rr] = mp[tm][r];
                pn[rr] = mn[tm][r];
            }
    }
}

// ---------------------------------------------------------------- tail:
// combine 16 slices (coalesced), hinge, CE sum -> atomic partials; last
// block runs the Lambert-W scalar.
__global__ __launch_bounds__(256) void k_tail(const float* __restrict__ sq,
                                              const float* __restrict__ ce,
                                              const float* __restrict__ pmax,
                                              const float* __restrict__ pmin,
                                              float* __restrict__ sums,
                                              unsigned* __restrict__ cnt,
                                              float* __restrict__ out) {
    __shared__ float sh[4], sc[4];
    __shared__ unsigned lastFlag;
    const int tid = threadIdx.x;
    int i = blockIdx.x * 256 + tid;

    float vmax = -3.0e38f, vmin = 3.0e38f;
#pragma unroll
    for (int s = 0; s < 16; ++s) {
        vmax = fmaxf(vmax, pmax[s * NB + i]);
        vmin = fminf(vmin, pmin[s * NB + i]);
    }
    float sqi = sq[i];
    float ap = sqrtf(fmaxf(fmaxf(sqi + vmax, 0.0f), 1e-12f));
    float an = sqrtf(fmaxf(fmaxf(sqi + vmin, 0.0f), 1e-12f));
    float hs = fmaxf(ap - an + 0.3f, 0.0f);
    float cs = ce[i];
#pragma unroll
    for (int off = 32; off; off >>= 1) {
        hs += __shfl_xor(hs, off);
        cs += __shfl_xor(cs, off);
    }
    int wv = tid >> 6;
    if ((tid & 63) == 0) { sh[wv] = hs; sc[wv] = cs; }
    __syncthreads();
    if (tid == 0) {
        float H = sh[0] + sh[1] + sh[2] + sh[3];
        float Cs = sc[0] + sc[1] + sc[2] + sc[3];
        atomicAdd(sums + 0, H);
        atomicAdd(sums + 1, Cs);
        __threadfence();
        unsigned prev = atomicAdd(cnt, 1u);
        lastFlag = (prev == (unsigned)(gridDim.x - 1));
    }
    __syncthreads();
    if (!lastFlag || tid != 0) return;

    // last block, thread 0: scalar Lambert-W tail
    double H = (double)atomicAdd(sums + 0, 0.0f);
    double Cs = (double)atomicAdd(sums + 1, 0.0f);
    const double E = 2.71828182845904523536;
    const double TAU = log(128.0);
    const double LAMd = 0.25;
    double l = H / (double)NB;
    double cev = Cs / (double)NB;
    double y = 0.5 * fmax(-2.0 / E, (l - TAU) / LAMd);
    double p = sqrt(fmax(2.0 * (E * y + 1.0), 0.0));
    double wn = -1.0 + p - p * p / 3.0 + (11.0 / 72.0) * p * p * p;
    double wlw = (y < 0.0) ? wn : log1p(fmax(y, 0.0));
#pragma unroll
    for (int it = 0; it < 10; ++it) {
        double ew = exp(wlw);
        double f = wlw * ew - y;
        double wp1 = wlw + 1.0;
        wlw = wlw - f / (ew * wp1 - (wlw + 2.0) * f / (2.0 * wp1));
    }
    double sigma = exp(-wlw);
    double lg = log(sigma);
    double loss = (cev - TAU) * sigma + LAMd * lg * lg;
    out[0] = (float)(loss / (double)NB);
}

// ---------------------------------------------------------------- launcher
extern "C" void kernel_launch(void* const* d_in, const int* in_sizes, int n_in,
                              void* d_out, int out_size, void* d_ws, size_t ws_size,
                              hipStream_t stream) {
    const float* x = (const float*)d_in[0];
    const int* tgt = (const int*)d_in[1];
    float* out = (float*)d_out;

    // ws: xq (NB*128 B = 1 MB) | sq | ce | sums[2] | cnt | pad | pmax | pmin
    unsigned char* xq = (unsigned char*)d_ws;
    float* sq = (float*)(xq + (size_t)NB * 128);
    float* ce = sq + NB;
    float* sums = ce + NB;
    unsigned* cnt = (unsigned*)(sums + 2);
    float* pmax = (float*)(cnt + 62);              // keep 256-B alignment
    float* pmin = pmax + (size_t)16 * NB;

    k_prep<<<NB / 8, 256, 0, stream>>>(x, tgt, (unsigned*)xq, sq, ce, sums, cnt);
    dim3 grid(NB / 64, NJS);
    k_trip<<<grid, 256, 0, stream>>>(xq, tgt, sq, pmax, pmin);
    k_tail<<<NB / 256, 256, 0, stream>>>(sq, ce, pmax, pmin, sums, cnt, out);
}

// Round 9
// 83.897 us; speedup vs baseline: 1.0472x; 1.0472x over previous
//
#include <hip/hip_runtime.h>
#include <math.h>

#define NB 8192
#define NC 128
#define NJS 8          // j-slices (grid.y); slice = 1024 cols
#define JPT 8          // j-tiles of 128 per slice

typedef float v4f __attribute__((ext_vector_type(4)));
typedef int   v8i __attribute__((ext_vector_type(8)));   // 32 fp8 (8 VGPRs)

// ---------------------------------------------------------------- prep:
// per row: fp8 e4m3 cast (packed 4/lane), sum-of-squares (fp32), CE term
// (fp32); zero sums/cnt. 8 rows per 256-thr block, 32 lanes per row.
__global__ __launch_bounds__(256) void k_prep(const float* __restrict__ x,
                                              const int* __restrict__ tgt,
                                              unsigned* __restrict__ xq,   // NB*32 uints (4 fp8 each)
                                              float* __restrict__ sq,
                                              float* __restrict__ ce,
                                              float* __restrict__ sums,
                                              unsigned* __restrict__ cnt) {
    int row = blockIdx.x * 8 + (threadIdx.x >> 5);
    int l = threadIdx.x & 31;
    float4 v = ((const float4*)(x + row * NC))[l];
    unsigned p = __builtin_amdgcn_cvt_pk_fp8_f32(v.x, v.y, 0, false);
    p = __builtin_amdgcn_cvt_pk_fp8_f32(v.z, v.w, p, true);
    xq[row * 32 + l] = p;

    float ss = fmaf(v.x, v.x, fmaf(v.y, v.y, fmaf(v.z, v.z, v.w * v.w)));
    float mx = fmaxf(fmaxf(v.x, v.y), fmaxf(v.z, v.w));
#pragma unroll
    for (int off = 16; off; off >>= 1) {        // offsets <32: stay within half-wave
        ss += __shfl_xor(ss, off);
        mx = fmaxf(mx, __shfl_xor(mx, off));
    }
    float es = expf(v.x - mx) + expf(v.y - mx) + expf(v.z - mx) + expf(v.w - mx);
#pragma unroll
    for (int off = 16; off; off >>= 1) es += __shfl_xor(es, off);
    if (l == 0) {
        sq[row] = ss;
        ce[row] = mx + logf(es) - x[row * NC + tgt[row]];
    }
    if (blockIdx.x == 0 && threadIdx.x < 4) {
        if (threadIdx.x < 2) sums[threadIdx.x] = 0.0f;
        if (threadIdx.x == 2) *cnt = 0u;
    }
}

// ---------------------------------------------------------------- triplet:
// FP8 E4M3 MX-scaled MFMA GEMM (16x16x128_f8f6f4, unit E8M0 scales -> plain
// fp8 dot at 2x the non-scaled rate; ONE MFMA covers K=128). 64x128 block
// tile (wave = 32x64), A in regs (v8i: k = quad*32 + byte), B double-
// buffered (2 x 16 KB) + metadata (8 KB) = 40 KB LDS => 4 blocks/CU, grid
// 1024 exactly resident. Loop: barrier (drains prefetch issued one full
// iteration ago ~ free) -> issue prefetch jt+1 -> compute jt. B staged
// with 16-B chunk XOR swizzle on the GLOBAL source address; b-frag = two
// ds_read_b128 at physical chunk (logical ^ (col&7)) — full LDS BW.
__global__ __launch_bounds__(256, 4) void k_trip(const unsigned char* __restrict__ xq,
                                                 const int* __restrict__ tgt,
                                                 const float* __restrict__ sq,
                                                 float* __restrict__ pmax,   // [16][NB]
                                                 float* __restrict__ pmin) { // [16][NB]
    __shared__ unsigned char Bs[2][128 * 128];  // 2 x 16 KB
    __shared__ float sqs[1024];                 // 4 KB  (block's j-slice sq)
    __shared__ int   tjs[1024];                 // 4 KB  (block's j-slice tgt)

    const int tid = threadIdx.x;
    const int lane = tid & 63;
    const int w = tid >> 6;           // wave 0..3
    const int rh = w >> 1;            // row half (32 rows)
    const int ch = w & 1;             // col half (64 cols)
    const int i0 = blockIdx.x * 64;
    const int jbase = blockIdx.y * 1024;
    const int m = lane & 15;
    const int quad = lane >> 4;

    // ---- stage j-slice metadata via async-LDS ----
    __builtin_amdgcn_global_load_lds(
        (const __attribute__((address_space(1))) unsigned*)((const unsigned*)(sq + jbase) + (w * 64 + lane) * 4),
        (__attribute__((address_space(3))) unsigned*)(sqs + w * 256),
        16, 0, 0);
    __builtin_amdgcn_global_load_lds(
        (const __attribute__((address_space(1))) unsigned*)((const unsigned*)(tgt + jbase) + (w * 64 + lane) * 4),
        (__attribute__((address_space(3))) unsigned*)(tjs + w * 256),
        16, 0, 0);

    // ---- stage B tile 0 into buffer 0 (async) ----
#pragma unroll
    for (int c = 0; c < 4; ++c) {
        int L = w * 256 + c * 64 + lane;          // 16-B chunk index 0..1023
        int col = L >> 3, cc = L & 7;
        const unsigned char* src = xq + (size_t)(jbase + col) * 128 + ((cc ^ (col & 7)) << 4);
        __builtin_amdgcn_global_load_lds(
            (const __attribute__((address_space(1))) unsigned*)src,
            (__attribute__((address_space(3))) unsigned*)(&Bs[0][0] + (w * 256 + c * 64) * 16),
            16, 0, 0);
    }

    // ---- A fragments straight into registers (32 B/frag, once per block) ----
    v8i a[2];
#pragma unroll
    for (int tm = 0; tm < 2; ++tm) {
        int row = i0 + rh * 32 + tm * 16 + m;
        a[tm] = *(const v8i*)(xq + (size_t)row * 128 + quad * 32);
    }

    // ---- anchor targets for this lane's output rows ----
    int ti[2][4];
#pragma unroll
    for (int tm = 0; tm < 2; ++tm)
#pragma unroll
        for (int r = 0; r < 4; ++r)
            ti[tm][r] = tgt[i0 + rh * 32 + tm * 16 + quad * 4 + r];

    float mp[2][4], mn[2][4];
#pragma unroll
    for (int tm = 0; tm < 2; ++tm)
#pragma unroll
        for (int r = 0; r < 4; ++r) { mp[tm][r] = -3.0e38f; mn[tm][r] = 3.0e38f; }

#pragma unroll 2
    for (int jt = 0; jt < JPT; ++jt) {
        // drains the prefetch issued one full iteration ago (~free) and
        // ensures all waves are done reading the buffer we're about to fill
        __syncthreads();

        // ---- early-issue prefetch of NEXT B tile into the other buffer ----
        if (jt + 1 < JPT) {
            int jn = jbase + (jt + 1) * 128;
            unsigned char* Bnxt = &Bs[(jt + 1) & 1][0];
#pragma unroll
            for (int c = 0; c < 4; ++c) {
                int L = w * 256 + c * 64 + lane;
                int col = L >> 3, cc = L & 7;
                const unsigned char* src = xq + (size_t)(jn + col) * 128 + ((cc ^ (col & 7)) << 4);
                __builtin_amdgcn_global_load_lds(
                    (const __attribute__((address_space(1))) unsigned*)src,
                    (__attribute__((address_space(3))) unsigned*)(Bnxt + (w * 256 + c * 64) * 16),
                    16, 0, 0);
            }
        }

        const unsigned char* Bcur = &Bs[jt & 1][0];

        // ---- column metadata from LDS ----
        float sqj[4]; int tj[4];
#pragma unroll
        for (int tn = 0; tn < 4; ++tn) {
            int cloc = jt * 128 + ch * 64 + tn * 16 + m;
            sqj[tn] = sqs[cloc];
            tj[tn] = tjs[cloc];
        }

        // ---- b fragments: 32 B/lane = two b128 reads (XOR-swizzled) ----
        v8i b[4];
#pragma unroll
        for (int tn = 0; tn < 4; ++tn) {
            int col = ch * 64 + tn * 16 + m;
            int base = col * 128;
            int c0 = (((quad * 2) ^ (col & 7)) << 4);
            int c1 = (((quad * 2 + 1) ^ (col & 7)) << 4);
            *(int4*)&b[tn] = *(const int4*)(Bcur + base + c0);
            *((int4*)&b[tn] + 1) = *(const int4*)(Bcur + base + c1);
        }

        // ---- one MX MFMA per (tm,tn) covers all K=128; scales = 1.0 ----
        v4f acc[2][4];
        v4f z = {0.0f, 0.0f, 0.0f, 0.0f};
#pragma unroll
        for (int tm = 0; tm < 2; ++tm)
#pragma unroll
            for (int tn = 0; tn < 4; ++tn)
                acc[tm][tn] = __builtin_amdgcn_mfma_scale_f32_16x16x128_f8f6f4(
                    a[tm], b[tn], z, 0, 0, 0, 0x7f7f7f7f, 0, 0x7f7f7f7f);

        // ---- fused epilogue: v = sqj - 2*dot (sqi added in k_tail) ----
#pragma unroll
        for (int tn = 0; tn < 4; ++tn) {
#pragma unroll
            for (int tm = 0; tm < 2; ++tm)
#pragma unroll
                for (int r = 0; r < 4; ++r) {
                    float v = fmaf(-2.0f, acc[tm][tn][r], sqj[tn]);
                    bool pos = (tj[tn] == ti[tm][r]);
                    mp[tm][r] = fmaxf(mp[tm][r], pos ? v : -3.0e38f);
                    mn[tm][r] = fminf(mn[tm][r], pos ? 3.0e38f : v);
                }
        }
    }

    // ---- reduce across the 16 lanes (lane&15) sharing each output row ----
#pragma unroll
    for (int off = 1; off < 16; off <<= 1) {
#pragma unroll
        for (int tm = 0; tm < 2; ++tm)
#pragma unroll
            for (int r = 0; r < 4; ++r) {
                mp[tm][r] = fmaxf(mp[tm][r], __shfl_xor(mp[tm][r], off));
                mn[tm][r] = fminf(mn[tm][r], __shfl_xor(mn[tm][r], off));
            }
    }
    // ---- plain stores to this wave's private (slice, row-range) ----
    if (m == 0) {
        int slice = blockIdx.y * 2 + ch;
        float* pm = pmax + (size_t)slice * NB + i0 + rh * 32;
        float* pn = pmin + (size_t)slice * NB + i0 + rh * 32;
#pragma unroll
        for (int tm = 0; tm < 2; ++tm)
#pragma unroll
            for (int r = 0; r < 4; ++r) {
                int rr = tm * 16 + quad * 4 + r;
                pm[rr] = mp[tm][r];
                pn[rr] = mn[tm][r];
            }
    }
}

// ---------------------------------------------------------------- tail:
// combine 16 slices (coalesced), hinge, CE sum -> atomic partials; last
// block runs the Lambert-W scalar.
__global__ __launch_bounds__(256) void k_tail(const float* __restrict__ sq,
                                              const float* __restrict__ ce,
                                              const float* __restrict__ pmax,
                                              const float* __restrict__ pmin,
                                              float* __restrict__ sums,
                                              unsigned* __restrict__ cnt,
                                              float* __restrict__ out) {
    __shared__ float sh[4], sc[4];
    __shared__ unsigned lastFlag;
    const int tid = threadIdx.x;
    int i = blockIdx.x * 256 + tid;

    float vmax = -3.0e38f, vmin = 3.0e38f;
#pragma unroll
    for (int s = 0; s < 16; ++s) {
        vmax = fmaxf(vmax, pmax[s * NB + i]);
        vmin = fminf(vmin, pmin[s * NB + i]);
    }
    float sqi = sq[i];
    float ap = sqrtf(fmaxf(fmaxf(sqi + vmax, 0.0f), 1e-12f));
    float an = sqrtf(fmaxf(fmaxf(sqi + vmin, 0.0f), 1e-12f));
    float hs = fmaxf(ap - an + 0.3f, 0.0f);
    float cs = ce[i];
#pragma unroll
    for (int off = 32; off; off >>= 1) {
        hs += __shfl_xor(hs, off);
        cs += __shfl_xor(cs, off);
    }
    int wv = tid >> 6;
    if ((tid & 63) == 0) { sh[wv] = hs; sc[wv] = cs; }
    __syncthreads();
    if (tid == 0) {
        float H = sh[0] + sh[1] + sh[2] + sh[3];
        float Cs = sc[0] + sc[1] + sc[2] + sc[3];
        atomicAdd(sums + 0, H);
        atomicAdd(sums + 1, Cs);
        __threadfence();
        unsigned prev = atomicAdd(cnt, 1u);
        lastFlag = (prev == (unsigned)(gridDim.x - 1));
    }
    __syncthreads();
    if (!lastFlag || tid != 0) return;

    // last block, thread 0: scalar Lambert-W tail
    double H = (double)atomicAdd(sums + 0, 0.0f);
    double Cs = (double)atomicAdd(sums + 1, 0.0f);
    const double E = 2.71828182845904523536;
    const double TAU = log(128.0);
    const double LAMd = 0.25;
    double l = H / (double)NB;
    double cev = Cs / (double)NB;
    double y = 0.5 * fmax(-2.0 / E, (l - TAU) / LAMd);
    double p = sqrt(fmax(2.0 * (E * y + 1.0), 0.0));
    double wn = -1.0 + p - p * p / 3.0 + (11.0 / 72.0) * p * p * p;
    double wlw = (y < 0.0) ? wn : log1p(fmax(y, 0.0));
#pragma unroll
    for (int it = 0; it < 10; ++it) {
        double ew = exp(wlw);
        double f = wlw * ew - y;
        double wp1 = wlw + 1.0;
        wlw = wlw - f / (ew * wp1 - (wlw + 2.0) * f / (2.0 * wp1));
    }
    double sigma = exp(-wlw);
    double lg = log(sigma);
    double loss = (cev - TAU) * sigma + LAMd * lg * lg;
    out[0] = (float)(loss / (double)NB);
}

// ---------------------------------------------------------------- launcher
extern "C" void kernel_launch(void* const* d_in, const int* in_sizes, int n_in,
                              void* d_out, int out_size, void* d_ws, size_t ws_size,
                              hipStream_t stream) {
    const float* x = (const float*)d_in[0];
    const int* tgt = (const int*)d_in[1];
    float* out = (float*)d_out;

    // ws: xq (NB*128 B = 1 MB) | sq | ce | sums[2] | cnt | pad | pmax | pmin
    unsigned char* xq = (unsigned char*)d_ws;
    float* sq = (float*)(xq + (size_t)NB * 128);
    float* ce = sq + NB;
    float* sums = ce + NB;
    unsigned* cnt = (unsigned*)(sums + 2);
    float* pmax = (float*)(cnt + 62);              // keep 256-B alignment
    float* pmin = pmax + (size_t)16 * NB;

    k_prep<<<NB / 8, 256, 0, stream>>>(x, tgt, (unsigned*)xq, sq, ce, sums, cnt);
    dim3 grid(NB / 64, NJS);
    k_trip<<<grid, 256, 0, stream>>>(xq, tgt, sq, pmax, pmin);
    k_tail<<<NB / 256, 256, 0, stream>>>(sq, ce, pmax, pmin, sums, cnt, out);
}